// Round 1
// baseline (419.774 us; speedup 1.0000x reference)
//
#include <hip/hip_runtime.h>

typedef __attribute__((ext_vector_type(8))) short short8;
typedef __attribute__((ext_vector_type(4))) short short4v;
typedef __attribute__((ext_vector_type(4))) float f32x4;

static __device__ __forceinline__ unsigned short f2bf(float f) {
  unsigned u = __float_as_uint(f);
  u = (u + 0x7FFFu + ((u >> 16) & 1u)) >> 16;  // RNE
  return (unsigned short)u;
}

// ---------------------------------------------------------------- convert
__global__ __launch_bounds__(256) void cvt_kernel(const float* __restrict__ s,
                                                  unsigned short* __restrict__ d,
                                                  int n4) {
  int i = blockIdx.x * 256 + threadIdx.x;
  if (i >= n4) return;
  float4 v = ((const float4*)s)[i];
  short4v o;
  o.x = (short)f2bf(v.x);
  o.y = (short)f2bf(v.y);
  o.z = (short)f2bf(v.z);
  o.w = (short)f2bf(v.w);
  *(short4v*)(d + 4L * i) = o;
}

// ---------------------------------------------------------------- GEMM C = A * W^T
// A: [M,768] bf16 (k contiguous), W: [768,768] bf16 (k contiguous)
// MODE 0: out bf16 [B,H,S,64]   (head-split, for Q/K)
// MODE 1: out bf16 [B,H,64,S]   (head-split transposed, for V)
// MODE 2: out fp32 [M,768] + bias
template <int MODE>
__global__ __launch_bounds__(256) void gemm_bt(const unsigned short* __restrict__ A,
                                               const unsigned short* __restrict__ W,
                                               const float* __restrict__ bias,
                                               void* __restrict__ outp) {
  constexpr int K = 768;
  __shared__ unsigned short As[128 * 40];  // pad 32->40: 2-way bank aliasing only
  __shared__ unsigned short Bs[128 * 40];
  const int tid = threadIdx.x;
  const int m0 = (blockIdx.x & 63) << 7;
  const int n0 = (blockIdx.x >> 6) << 7;
  const int wave = tid >> 6, lane = tid & 63;
  const int ln = lane & 15, quad = lane >> 4;
  const int wm = (wave & 1) << 6, wn = (wave >> 1) << 6;

  const int ar0 = tid >> 2, ac0 = (tid & 3) << 3;
  const int ar1 = ar0 + 64;

  f32x4 acc[4][4] = {};

  const unsigned short* Ap0 = A + (long)(m0 + ar0) * K + ac0;
  const unsigned short* Ap1 = A + (long)(m0 + ar1) * K + ac0;
  const unsigned short* Wp0 = W + (long)(n0 + ar0) * K + ac0;
  const unsigned short* Wp1 = W + (long)(n0 + ar1) * K + ac0;

  for (int k0 = 0; k0 < K; k0 += 32) {
    short8 a0 = *(const short8*)(Ap0 + k0);
    short8 a1 = *(const short8*)(Ap1 + k0);
    short8 b0 = *(const short8*)(Wp0 + k0);
    short8 b1 = *(const short8*)(Wp1 + k0);
    __syncthreads();
    *(short8*)(As + ar0 * 40 + ac0) = a0;
    *(short8*)(As + ar1 * 40 + ac0) = a1;
    *(short8*)(Bs + ar0 * 40 + ac0) = b0;
    *(short8*)(Bs + ar1 * 40 + ac0) = b1;
    __syncthreads();
    short8 af[4], bfr[4];
#pragma unroll
    for (int mi = 0; mi < 4; mi++)
      af[mi] = *(const short8*)(As + (wm + mi * 16 + ln) * 40 + quad * 8);
#pragma unroll
    for (int ni = 0; ni < 4; ni++)
      bfr[ni] = *(const short8*)(Bs + (wn + ni * 16 + ln) * 40 + quad * 8);
#pragma unroll
    for (int mi = 0; mi < 4; mi++)
#pragma unroll
      for (int ni = 0; ni < 4; ni++)
        acc[mi][ni] =
            __builtin_amdgcn_mfma_f32_16x16x32_bf16(af[mi], bfr[ni], acc[mi][ni], 0, 0, 0);
  }

#pragma unroll
  for (int mi = 0; mi < 4; mi++) {
#pragma unroll
    for (int ni = 0; ni < 4; ni++) {
      f32x4 v = acc[mi][ni];
      const int ng = n0 + wn + ni * 16 + ln;
#pragma unroll
      for (int r = 0; r < 4; r++) {
        const int mg = m0 + wm + mi * 16 + quad * 4 + r;  // C-layout: row=quad*4+reg
        if (MODE == 2) {
          ((float*)outp)[(long)mg * 768 + ng] = v[r] + bias[ng];
        } else {
          const int b = mg >> 11, s = mg & 2047;
          const int h = ng >> 6, d = ng & 63;
          long idx;
          if (MODE == 0)
            idx = ((long)(b * 12 + h) * 2048 + s) * 64 + d;
          else
            idx = ((long)(b * 12 + h) * 64 + d) * 2048 + s;
          ((unsigned short*)outp)[idx] = f2bf(v[r]);
        }
      }
    }
  }
}

// ---------------------------------------------------------------- flash attention
// Qh,Kh: [B,H,S,64] bf16; Vt: [B,H,64,S] bf16; out: [B,S,768] bf16 (heads merged)
__global__ __launch_bounds__(256) void attn_kernel(const unsigned short* __restrict__ Qh,
                                                   const unsigned short* __restrict__ Kh,
                                                   const unsigned short* __restrict__ Vt,
                                                   unsigned short* __restrict__ Ob) {
  constexpr int S = 2048;
  constexpr float CEXP = 0.18033688011112042f;  // (1/8)*log2(e)
  __shared__ unsigned short Qs[64 * 72];
  __shared__ unsigned short Ks[128 * 72];
  __shared__ unsigned short Vs[64 * 136];
  __shared__ unsigned short Ps[4 * 16 * 136];

  const int bx = blockIdx.x;
  const int qt = bx & 31;
  const int bh = bx >> 5;
  const int h = bh % 12, b = bh / 12;
  const int tid = threadIdx.x, wave = tid >> 6, lane = tid & 63;
  const int ln = lane & 15, quad = lane >> 4;

  const unsigned short* Qg = Qh + ((long)(b * 12 + h) * S + qt * 64) * 64;
  const unsigned short* Kg = Kh + (long)(b * 12 + h) * S * 64;
  const unsigned short* Vg = Vt + (long)(b * 12 + h) * 64 * S;

  // stage Q (64x64, contiguous 8KB)
#pragma unroll
  for (int i = 0; i < 2; i++) {
    int c = tid + i * 256;
    short8 v = *(const short8*)(Qg + c * 8);
    *(short8*)(Qs + (c >> 3) * 72 + (c & 7) * 8) = v;
  }
  __syncthreads();
  short8 aQ0 = *(const short8*)(Qs + (wave * 16 + ln) * 72 + quad * 8);
  short8 aQ1 = *(const short8*)(Qs + (wave * 16 + ln) * 72 + 32 + quad * 8);

  float m_r[4], l_r[4];
  f32x4 O[4] = {};
#pragma unroll
  for (int r = 0; r < 4; r++) {
    m_r[r] = -1e30f;
    l_r[r] = 0.f;
  }

  const int nkt = (qt >> 1) + 1;
  const int rowb = qt * 64 + wave * 16 + quad * 4;
  unsigned short* Pw = Ps + wave * (16 * 136);

  for (int kt = 0; kt < nkt; kt++) {
    short8 kc[4], vc[4];
#pragma unroll
    for (int i = 0; i < 4; i++) {
      int c = tid + i * 256;
      kc[i] = *(const short8*)(Kg + (long)kt * 8192 + c * 8);
      vc[i] = *(const short8*)(Vg + (long)(c >> 4) * S + kt * 128 + (c & 15) * 8);
    }
    __syncthreads();
#pragma unroll
    for (int i = 0; i < 4; i++) {
      int c = tid + i * 256;
      *(short8*)(Ks + (c >> 3) * 72 + (c & 7) * 8) = kc[i];
      *(short8*)(Vs + (c >> 4) * 136 + (c & 15) * 8) = vc[i];
    }
    __syncthreads();

    // S = Q K^T  (wave: 16 rows x 128 cols)
    f32x4 sf[8] = {};
#pragma unroll
    for (int ni = 0; ni < 8; ni++) {
      short8 bK0 = *(const short8*)(Ks + (ni * 16 + ln) * 72 + quad * 8);
      sf[ni] = __builtin_amdgcn_mfma_f32_16x16x32_bf16(aQ0, bK0, sf[ni], 0, 0, 0);
      short8 bK1 = *(const short8*)(Ks + (ni * 16 + ln) * 72 + 32 + quad * 8);
      sf[ni] = __builtin_amdgcn_mfma_f32_16x16x32_bf16(aQ1, bK1, sf[ni], 0, 0, 0);
    }

    const bool diag = (kt == nkt - 1);
    float alpha[4];
#pragma unroll
    for (int r = 0; r < 4; r++) {
      const int rg = rowb + r;
      float mx = -1e30f;
#pragma unroll
      for (int ni = 0; ni < 8; ni++) {
        float v = sf[ni][r];
        if (diag) {
          int cg = kt * 128 + ni * 16 + ln;
          if (cg > rg) {
            v = -1e30f;
            sf[ni][r] = v;
          }
        }
        mx = fmaxf(mx, v);
      }
      // row max/sum live across the 16 lanes of the quad (C-layout cols)
      mx = fmaxf(mx, __shfl_xor(mx, 1));
      mx = fmaxf(mx, __shfl_xor(mx, 2));
      mx = fmaxf(mx, __shfl_xor(mx, 4));
      mx = fmaxf(mx, __shfl_xor(mx, 8));
      float mnew = fmaxf(m_r[r], mx);
      alpha[r] = exp2f((m_r[r] - mnew) * CEXP);
      m_r[r] = mnew;
      float sum = 0.f;
#pragma unroll
      for (int ni = 0; ni < 8; ni++) {
        float p = exp2f((sf[ni][r] - mnew) * CEXP);
        sf[ni][r] = p;
        sum += p;
      }
      sum += __shfl_xor(sum, 1);
      sum += __shfl_xor(sum, 2);
      sum += __shfl_xor(sum, 4);
      sum += __shfl_xor(sum, 8);
      l_r[r] = l_r[r] * alpha[r] + sum;
    }

    // C-layout -> A-layout via per-wave LDS round trip (m120 pattern)
#pragma unroll
    for (int ni = 0; ni < 8; ni++)
#pragma unroll
      for (int r = 0; r < 4; r++)
        Pw[(quad * 4 + r) * 136 + ni * 16 + ln] = f2bf(sf[ni][r]);

#pragma unroll
    for (int di = 0; di < 4; di++)
#pragma unroll
      for (int r = 0; r < 4; r++)
        O[di][r] *= alpha[r];

    __builtin_amdgcn_s_waitcnt(0xC07F);  // lgkmcnt(0): P writes visible in-wave

    // O += P * V   (A=P[16x128], B=Vt rows as n=depth)
#pragma unroll
    for (int kk = 0; kk < 4; kk++) {
      short8 aP = *(const short8*)(Pw + ln * 136 + kk * 32 + quad * 8);
#pragma unroll
      for (int di = 0; di < 4; di++) {
        short8 bV = *(const short8*)(Vs + (di * 16 + ln) * 136 + kk * 32 + quad * 8);
        O[di] = __builtin_amdgcn_mfma_f32_16x16x32_bf16(aP, bV, O[di], 0, 0, 0);
      }
    }
  }

  unsigned short* op = Ob + ((long)b * S + qt * 64 + wave * 16 + quad * 4) * 768 + h * 64;
#pragma unroll
  for (int r = 0; r < 4; r++) {
    float rl = 1.0f / l_r[r];
#pragma unroll
    for (int di = 0; di < 4; di++)
      op[(long)r * 768 + di * 16 + ln] = f2bf(O[di][r] * rl);
  }
}

// ---------------------------------------------------------------- launch
extern "C" void kernel_launch(void* const* d_in, const int* in_sizes, int n_in,
                              void* d_out, int out_size, void* d_ws, size_t ws_size,
                              hipStream_t stream) {
  const float* q = (const float*)d_in[0];
  const float* k = (const float*)d_in[1];
  const float* v = (const float*)d_in[2];
  // d_in[3] = mask: causal triu(k=1) by construction — implemented analytically
  const float* wq = (const float*)d_in[4];
  const float* wk = (const float*)d_in[5];
  const float* wv = (const float*)d_in[6];
  const float* wd = (const float*)d_in[7];
  const float* bd = (const float*)d_in[8];
  float* out = (float*)d_out;

  const long QKV = 4L * 2048 * 768;  // 6291456
  const long WN = 768L * 768;        // 589824
  if (ws_size < (size_t)(7 * QKV + 4 * WN) * 2) return;  // ~88.5 MB needed

  unsigned short* qb = (unsigned short*)d_ws;
  unsigned short* kb = qb + QKV;
  unsigned short* vb = kb + QKV;
  unsigned short* wqb = vb + QKV;
  unsigned short* wkb = wqb + WN;
  unsigned short* wvb = wkb + WN;
  unsigned short* wdb = wvb + WN;
  unsigned short* qh = wdb + WN;
  unsigned short* kh = qh + QKV;
  unsigned short* vt = kh + QKV;
  unsigned short* at = vt + QKV;

  const int gq = (int)(QKV / 4 / 256);  // 6144
  const int gw = (int)(WN / 4 / 256);   // 576
  cvt_kernel<<<gq, 256, 0, stream>>>(q, qb, (int)(QKV / 4));
  cvt_kernel<<<gq, 256, 0, stream>>>(k, kb, (int)(QKV / 4));
  cvt_kernel<<<gq, 256, 0, stream>>>(v, vb, (int)(QKV / 4));
  cvt_kernel<<<gw, 256, 0, stream>>>(wq, wqb, (int)(WN / 4));
  cvt_kernel<<<gw, 256, 0, stream>>>(wk, wkb, (int)(WN / 4));
  cvt_kernel<<<gw, 256, 0, stream>>>(wv, wvb, (int)(WN / 4));
  cvt_kernel<<<gw, 256, 0, stream>>>(wd, wdb, (int)(WN / 4));

  gemm_bt<0><<<384, 256, 0, stream>>>(qb, wqb, nullptr, qh);
  gemm_bt<0><<<384, 256, 0, stream>>>(kb, wkb, nullptr, kh);
  gemm_bt<1><<<384, 256, 0, stream>>>(vb, wvb, nullptr, vt);
  attn_kernel<<<1536, 256, 0, stream>>>(qh, kh, vt, at);
  gemm_bt<2><<<384, 256, 0, stream>>>(at, wdb, bd, out);
}

// Round 2
// 354.126 us; speedup vs baseline: 1.1854x; 1.1854x over previous
//
#include <hip/hip_runtime.h>

typedef __attribute__((ext_vector_type(8))) short short8;
typedef __attribute__((ext_vector_type(4))) short short4v;
typedef __attribute__((ext_vector_type(4))) float f32x4;
typedef __attribute__((ext_vector_type(4))) unsigned int uint4v;

static __device__ __forceinline__ unsigned short f2bf(float f) {
  unsigned u = __float_as_uint(f);
  u = (u + 0x7FFFu + ((u >> 16) & 1u)) >> 16;  // RNE
  return (unsigned short)u;
}

#define GLDS(g, l)                                                              \
  __builtin_amdgcn_global_load_lds((const __attribute__((address_space(1))) void*)(g), \
                                   (__attribute__((address_space(3))) void*)(l), 16, 0, 0)

// ---------------------------------------------------------------- converts
__global__ __launch_bounds__(256) void cvt_qkv(const float* __restrict__ q,
                                               const float* __restrict__ k,
                                               const float* __restrict__ v,
                                               unsigned short* __restrict__ oq,
                                               unsigned short* __restrict__ ok,
                                               unsigned short* __restrict__ ov) {
  int bx = blockIdx.x;
  int seg = bx / 6144;
  int t = bx - seg * 6144;
  const float* s = seg == 0 ? q : seg == 1 ? k : v;
  unsigned short* d = seg == 0 ? oq : seg == 1 ? ok : ov;
  long i = (long)t * 256 + threadIdx.x;
  float4 val = ((const float4*)s)[i];
  short4v o;
  o.x = (short)f2bf(val.x);
  o.y = (short)f2bf(val.y);
  o.z = (short)f2bf(val.z);
  o.w = (short)f2bf(val.w);
  *(short4v*)(d + 4 * i) = o;
}

__global__ __launch_bounds__(256) void cvt_w(const float* __restrict__ w0,
                                             const float* __restrict__ w1,
                                             const float* __restrict__ w2,
                                             const float* __restrict__ w3,
                                             unsigned short* __restrict__ o0,
                                             unsigned short* __restrict__ o1,
                                             unsigned short* __restrict__ o2,
                                             unsigned short* __restrict__ o3) {
  int bx = blockIdx.x;
  int seg = bx / 576;
  int t = bx - seg * 576;
  const float* s = seg == 0 ? w0 : seg == 1 ? w1 : seg == 2 ? w2 : w3;
  unsigned short* d = seg == 0 ? o0 : seg == 1 ? o1 : seg == 2 ? o2 : o3;
  long i = (long)t * 256 + threadIdx.x;
  float4 val = ((const float4*)s)[i];
  short4v o;
  o.x = (short)f2bf(val.x);
  o.y = (short)f2bf(val.y);
  o.z = (short)f2bf(val.z);
  o.w = (short)f2bf(val.w);
  *(short4v*)(d + 4 * i) = o;
}

// ---------------------------------------------------------------- GEMM core (m97-style)
// A [M,768] bf16 k-contig, W [768,768] bf16 k-contig; 128x128 tile; BK=32.
static __device__ __forceinline__ void gemm_core(const unsigned short* __restrict__ A,
                                                 const unsigned short* __restrict__ W,
                                                 unsigned short* As, unsigned short* Bs,
                                                 int m0, int n0, f32x4 (&acc)[4][4]) {
  constexpr int K = 768;
  const int tid = threadIdx.x, lane = tid & 63;
  const int ln = lane & 15, quad = lane >> 4;
  const int wave = tid >> 6;
  const int wm = (wave & 1) << 6, wn = (wave >> 1) << 6;

  const int o0 = tid << 4;           // bytes, issue 0 (rows 0..63)
  const int o1 = 4096 + (tid << 4);  // issue 1 (rows 64..127)
  const int r0 = o0 >> 6, c0 = (o0 >> 4) & 3;
  const int r1 = o1 >> 6, c1 = (o1 >> 4) & 3;
  const unsigned short* gA0 = A + (long)(m0 + r0) * K + c0 * 8;
  const unsigned short* gA1 = A + (long)(m0 + r1) * K + c1 * 8;
  const unsigned short* gB0 = W + (long)(n0 + r0) * K + c0 * 8;
  const unsigned short* gB1 = W + (long)(n0 + r1) * K + c1 * 8;
  unsigned short* lA0 = As + (o0 >> 1);
  unsigned short* lA1 = As + (o1 >> 1);
  unsigned short* lB0 = Bs + (o0 >> 1);
  unsigned short* lB1 = Bs + (o1 >> 1);

  for (int k0 = 0; k0 < K; k0 += 32) {
    __syncthreads();
    GLDS(gA0 + k0, lA0);
    GLDS(gA1 + k0, lA1);
    GLDS(gB0 + k0, lB0);
    GLDS(gB1 + k0, lB1);
    __syncthreads();
    short8 af[4], bfr[4];
#pragma unroll
    for (int mi = 0; mi < 4; mi++)
      af[mi] = *(const short8*)(As + (wm + mi * 16 + ln) * 32 + quad * 8);
#pragma unroll
    for (int ni = 0; ni < 4; ni++)
      bfr[ni] = *(const short8*)(Bs + (wn + ni * 16 + ln) * 32 + quad * 8);
#pragma unroll
    for (int mi = 0; mi < 4; mi++)
#pragma unroll
      for (int ni = 0; ni < 4; ni++)
        acc[mi][ni] =
            __builtin_amdgcn_mfma_f32_16x16x32_bf16(af[mi], bfr[ni], acc[mi][ni], 0, 0, 0);
  }
}

// proj: op0/1 -> [B,H,S,64] (Q,K), op2 -> [B,H,64,S] (V^T)
__global__ __launch_bounds__(256) void proj_gemm(
    const unsigned short* __restrict__ Aq, const unsigned short* __restrict__ Ak,
    const unsigned short* __restrict__ Av, const unsigned short* __restrict__ Wq,
    const unsigned short* __restrict__ Wk, const unsigned short* __restrict__ Wv,
    unsigned short* __restrict__ Oq, unsigned short* __restrict__ Ok,
    unsigned short* __restrict__ Ov) {
  __shared__ unsigned short As[128 * 32];
  __shared__ unsigned short Bs[128 * 32];
  const int bx = blockIdx.x;
  const int op = bx / 384;
  const int t = bx - op * 384;
  const unsigned short* A = op == 0 ? Aq : op == 1 ? Ak : Av;
  const unsigned short* W = op == 0 ? Wq : op == 1 ? Wk : Wv;
  unsigned short* O = op == 0 ? Oq : op == 1 ? Ok : Ov;
  const int m0 = (t & 63) << 7, n0 = (t >> 6) << 7;

  f32x4 acc[4][4] = {};
  gemm_core(A, W, As, Bs, m0, n0, acc);

  const int lane = threadIdx.x & 63, wave = threadIdx.x >> 6;
  const int ln = lane & 15, quad = lane >> 4;
  const int wm = (wave & 1) << 6, wn = (wave >> 1) << 6;
#pragma unroll
  for (int mi = 0; mi < 4; mi++) {
#pragma unroll
    for (int ni = 0; ni < 4; ni++) {
      f32x4 v = acc[mi][ni];
      const int ng = n0 + wn + ni * 16 + ln;
      const int hh = ng >> 6, d = ng & 63;
#pragma unroll
      for (int r = 0; r < 4; r++) {
        const int mg = m0 + wm + mi * 16 + quad * 4 + r;
        const int bb = mg >> 11, s = mg & 2047;
        long idx;
        if (op < 2)
          idx = ((long)(bb * 12 + hh) * 2048 + s) * 64 + d;
        else
          idx = ((long)(bb * 12 + hh) * 64 + d) * 2048 + s;
        O[idx] = f2bf(v[r]);
      }
    }
  }
}

__global__ __launch_bounds__(256) void dense_gemm(const unsigned short* __restrict__ A,
                                                  const unsigned short* __restrict__ W,
                                                  const float* __restrict__ bias,
                                                  float* __restrict__ out) {
  __shared__ unsigned short As[128 * 32];
  __shared__ unsigned short Bs[128 * 32];
  const int t = blockIdx.x;
  const int m0 = (t & 63) << 7, n0 = (t >> 6) << 7;

  f32x4 acc[4][4] = {};
  gemm_core(A, W, As, Bs, m0, n0, acc);

  const int lane = threadIdx.x & 63, wave = threadIdx.x >> 6;
  const int ln = lane & 15, quad = lane >> 4;
  const int wm = (wave & 1) << 6, wn = (wave >> 1) << 6;
#pragma unroll
  for (int mi = 0; mi < 4; mi++) {
#pragma unroll
    for (int ni = 0; ni < 4; ni++) {
      f32x4 v = acc[mi][ni];
      const int ng = n0 + wn + ni * 16 + ln;
      const float bv = bias[ng];
#pragma unroll
      for (int r = 0; r < 4; r++) {
        const int mg = m0 + wm + mi * 16 + quad * 4 + r;
        out[(long)mg * 768 + ng] = v[r] + bv;
      }
    }
  }
}

// ---------------------------------------------------------------- flash attention (transposed)
// S^T = K Q^T; softmax over rows (keys) -> per-lane scalar m/l; P^T feeds PV as
// B-operand via quad-pair shuffles (no LDS round trip). O^T = V^T P^T.
// Block: pair of q-tiles (qt, 31-qt), 4 waves x 16 q-rows each, K-tile = 128.
__global__ __launch_bounds__(256, 3) void attn_kernel(const unsigned short* __restrict__ Qh,
                                                      const unsigned short* __restrict__ Kh,
                                                      const unsigned short* __restrict__ Vt,
                                                      unsigned short* __restrict__ outp) {
  constexpr int S = 2048;
  constexpr float CEXP = 0.18033688011112042f;  // (1/8)*log2(e)
  __shared__ unsigned short Ks[128 * 72];
  __shared__ unsigned short Vs[64 * 136];

  const int bx = blockIdx.x;
  const int pr = bx & 15;
  const int bh = bx >> 4;
  const int h = bh % 12, b = bh / 12;
  const int qtA = pr, qtB = 31 - pr;
  const int tid = threadIdx.x, wave = tid >> 6, lane = tid & 63;
  const int ln = lane & 15, quad = lane >> 4;

  const unsigned short* Qg = Qh + (long)(b * 12 + h) * S * 64;
  const unsigned short* Kg = Kh + (long)(b * 12 + h) * S * 64;
  const unsigned short* Vg = Vt + (long)(b * 12 + h) * 64 * S;

  const int qrA = qtA * 64 + wave * 16 + ln;
  const int qrB = qtB * 64 + wave * 16 + ln;

  // Q fragments (B-operand) in registers
  short8 bQa0 = *(const short8*)(Qg + qrA * 64 + quad * 8);
  short8 bQa1 = *(const short8*)(Qg + qrA * 64 + 32 + quad * 8);
  short8 bQb0 = *(const short8*)(Qg + qrB * 64 + quad * 8);
  short8 bQb1 = *(const short8*)(Qg + qrB * 64 + 32 + quad * 8);

  float mA = -1e30f, lA = 0.f, mB = -1e30f, lB = 0.f;
  f32x4 Oa[4] = {};
  f32x4 Obb[4] = {};
  unsigned pkA[8][2], pkB[8][2];

  const int nkA = (qtA >> 1) + 1;
  const int nkB = (qtB >> 1) + 1;
  const int l0 = ln + ((quad & 1) << 5);
  const bool hi = quad >= 2;

  for (int kt = 0; kt < nkB; kt++) {
    // ---- stage K (128x64) and V^T (64x128) cooperatively
    short8 kc[4], vc[4];
#pragma unroll
    for (int i = 0; i < 4; i++) {
      int c = tid + i * 256;
      kc[i] = *(const short8*)(Kg + (long)kt * 8192 + c * 8);
      vc[i] = *(const short8*)(Vg + (long)(c >> 4) * S + kt * 128 + (c & 15) * 8);
    }
    __syncthreads();
#pragma unroll
    for (int i = 0; i < 4; i++) {
      int c = tid + i * 256;
      *(short8*)(Ks + (c >> 3) * 72 + (c & 7) * 8) = kc[i];
      *(short8*)(Vs + (c >> 4) * 136 + (c & 15) * 8) = vc[i];
    }
    __syncthreads();

    const bool actA = kt < nkA;
    const bool dgA = (kt == nkA - 1);
    const bool dgB = (kt == nkB - 1);
    const int limA = actA ? (dgA ? ((qtA & 1) ? 8 : 4) : 8) : 0;
    const int limB = dgB ? ((qtB & 1) ? 8 : 4) : 8;
    const int limQ = limA > limB ? limA : limB;

    // ---- S^T = K Q^T, shared K fragment reads serve both segments
    f32x4 sa[8], sb[8];
#pragma unroll
    for (int ni = 0; ni < 8; ni++) {
      sa[ni] = (f32x4){0.f, 0.f, 0.f, 0.f};
      sb[ni] = (f32x4){0.f, 0.f, 0.f, 0.f};
    }
#pragma unroll
    for (int ni = 0; ni < 8; ni++) {
      if (ni < limQ) {
        short8 k0 = *(const short8*)(Ks + (ni * 16 + ln) * 72 + quad * 8);
        short8 k1 = *(const short8*)(Ks + (ni * 16 + ln) * 72 + 32 + quad * 8);
        if (ni < limA) {
          sa[ni] = __builtin_amdgcn_mfma_f32_16x16x32_bf16(k0, bQa0, sa[ni], 0, 0, 0);
          sa[ni] = __builtin_amdgcn_mfma_f32_16x16x32_bf16(k1, bQa1, sa[ni], 0, 0, 0);
        }
        if (ni < limB) {
          sb[ni] = __builtin_amdgcn_mfma_f32_16x16x32_bf16(k0, bQb0, sb[ni], 0, 0, 0);
          sb[ni] = __builtin_amdgcn_mfma_f32_16x16x32_bf16(k1, bQb1, sb[ni], 0, 0, 0);
        }
      }
    }

    // ---- online softmax over keys (rows): local 32 values + shfl_xor(16,32)
    auto soft = [&](f32x4* s, unsigned (&pk)[8][2], float& m, float& l, f32x4* O, int lim,
                    bool dg, int qrow) {
      if (dg) {
#pragma unroll
        for (int ni = 0; ni < 8; ni++)
          if (ni < lim)
#pragma unroll
            for (int r = 0; r < 4; r++) {
              int key = kt * 128 + ni * 16 + quad * 4 + r;
              if (key > qrow) s[ni][r] = -1e30f;
            }
      }
      float mx = -1e30f;
#pragma unroll
      for (int ni = 0; ni < 8; ni++)
        if (ni < lim)
          mx = fmaxf(mx, fmaxf(fmaxf(s[ni][0], s[ni][1]), fmaxf(s[ni][2], s[ni][3])));
      mx = fmaxf(mx, __shfl_xor(mx, 16));
      mx = fmaxf(mx, __shfl_xor(mx, 32));
      float mnew = fmaxf(m, mx);
      float alpha = exp2f((m - mnew) * CEXP);
      m = mnew;
      const float mc = mnew * CEXP;
      float sum = 0.f;
#pragma unroll
      for (int ni = 0; ni < 8; ni++) {
        if (ni < lim) {
          float p0 = exp2f(fmaf(s[ni][0], CEXP, -mc));
          float p1 = exp2f(fmaf(s[ni][1], CEXP, -mc));
          float p2 = exp2f(fmaf(s[ni][2], CEXP, -mc));
          float p3 = exp2f(fmaf(s[ni][3], CEXP, -mc));
          sum += (p0 + p1) + (p2 + p3);
          // truncate-pack to bf16 pairs (1 v_perm each)
          pk[ni][0] = __builtin_amdgcn_perm(__float_as_uint(p1), __float_as_uint(p0), 0x07060302u);
          pk[ni][1] = __builtin_amdgcn_perm(__float_as_uint(p3), __float_as_uint(p2), 0x07060302u);
        } else {
          pk[ni][0] = 0u;
          pk[ni][1] = 0u;
        }
      }
      sum += __shfl_xor(sum, 16);
      sum += __shfl_xor(sum, 32);
      l = l * alpha + sum;
#pragma unroll
      for (int di = 0; di < 4; di++) O[di] *= alpha;
    };
    if (actA) soft(sa, pkA, mA, lA, Oa, limA, dgA, qrA);
    soft(sb, pkB, mB, lB, Obb, limB, dgB, qrB);

    // ---- build P^T B-operand fragment for key-chunk kk via quad-pair shuffles
    auto mkB = [&](unsigned (&pk)[8][2], int kk) -> short8 {
      unsigned va0 = (unsigned)__shfl((int)pk[2 * kk][0], l0, 64);
      unsigned vb0 = (unsigned)__shfl((int)pk[2 * kk + 1][0], l0, 64);
      unsigned va1 = (unsigned)__shfl((int)pk[2 * kk][1], l0, 64);
      unsigned vb1 = (unsigned)__shfl((int)pk[2 * kk + 1][1], l0, 64);
      unsigned va2 = (unsigned)__shfl((int)pk[2 * kk][0], l0 + 16, 64);
      unsigned vb2 = (unsigned)__shfl((int)pk[2 * kk + 1][0], l0 + 16, 64);
      unsigned va3 = (unsigned)__shfl((int)pk[2 * kk][1], l0 + 16, 64);
      unsigned vb3 = (unsigned)__shfl((int)pk[2 * kk + 1][1], l0 + 16, 64);
      uint4v tv;
      tv.x = hi ? vb0 : va0;
      tv.y = hi ? vb1 : va1;
      tv.z = hi ? vb2 : va2;
      tv.w = hi ? vb3 : va3;
      return __builtin_bit_cast(short8, tv);
    };

    // ---- O^T += V^T P^T, shared V fragment reads serve both segments
#pragma unroll
    for (int kk = 0; kk < 4; kk++) {
      short8 Bb = mkB(pkB, kk);
      short8 Ba;
      if (actA) Ba = mkB(pkA, kk);
#pragma unroll
      for (int di = 0; di < 4; di++) {
        short8 aV = *(const short8*)(Vs + (di * 16 + ln) * 136 + kk * 32 + quad * 8);
        Obb[di] = __builtin_amdgcn_mfma_f32_16x16x32_bf16(aV, Bb, Obb[di], 0, 0, 0);
        if (actA) Oa[di] = __builtin_amdgcn_mfma_f32_16x16x32_bf16(aV, Ba, Oa[di], 0, 0, 0);
      }
    }
  }

  // ---- epilogue: O^T lane holds q=ln, d = di*16 + quad*4 + r (4 consecutive)
  auto epi = [&](f32x4* O, float l, int qrow) {
    float rl = 1.0f / l;
    unsigned short* op = outp + ((long)b * S + qrow) * 768 + h * 64 + quad * 4;
#pragma unroll
    for (int di = 0; di < 4; di++) {
      unsigned lo = (unsigned)f2bf(O[di][0] * rl) | ((unsigned)f2bf(O[di][1] * rl) << 16);
      unsigned hi2 = (unsigned)f2bf(O[di][2] * rl) | ((unsigned)f2bf(O[di][3] * rl) << 16);
      uint2 st;
      st.x = lo;
      st.y = hi2;
      *(uint2*)(op + di * 16) = st;
    }
  };
  epi(Oa, lA, qrA);
  epi(Obb, lB, qrB);
}

// ---------------------------------------------------------------- launch
extern "C" void kernel_launch(void* const* d_in, const int* in_sizes, int n_in,
                              void* d_out, int out_size, void* d_ws, size_t ws_size,
                              hipStream_t stream) {
  const float* q = (const float*)d_in[0];
  const float* k = (const float*)d_in[1];
  const float* v = (const float*)d_in[2];
  // d_in[3] = mask: causal triu(k=1) by construction — implemented analytically
  const float* wq = (const float*)d_in[4];
  const float* wk = (const float*)d_in[5];
  const float* wv = (const float*)d_in[6];
  const float* wd = (const float*)d_in[7];
  const float* bd = (const float*)d_in[8];
  float* out = (float*)d_out;

  const long QKV = 4L * 2048 * 768;  // 6291456
  const long WN = 768L * 768;        // 589824
  if (ws_size < (size_t)(7 * QKV + 4 * WN) * 2) return;

  unsigned short* qb = (unsigned short*)d_ws;
  unsigned short* kb = qb + QKV;
  unsigned short* vb = kb + QKV;
  unsigned short* wqb = vb + QKV;
  unsigned short* wkb = wqb + WN;
  unsigned short* wvb = wkb + WN;
  unsigned short* wdb = wvb + WN;
  unsigned short* qh = wdb + WN;
  unsigned short* kh = qh + QKV;
  unsigned short* vt = kh + QKV;
  unsigned short* at = vt + QKV;

  cvt_qkv<<<18432, 256, 0, stream>>>(q, k, v, qb, kb, vb);
  cvt_w<<<2304, 256, 0, stream>>>(wq, wk, wv, wd, wqb, wkb, wvb, wdb);
  proj_gemm<<<1152, 256, 0, stream>>>(qb, kb, vb, wqb, wkb, wvb, qh, kh, vt);
  attn_kernel<<<768, 256, 0, stream>>>(qh, kh, vt, at);
  dense_gemm<<<384, 256, 0, stream>>>(at, wdb, bd, out);
}

// Round 3
// 344.502 us; speedup vs baseline: 1.2185x; 1.0279x over previous
//
#include <hip/hip_runtime.h>

typedef __attribute__((ext_vector_type(8))) short short8;
typedef __attribute__((ext_vector_type(4))) short short4v;
typedef __attribute__((ext_vector_type(4))) float f32x4;
typedef __attribute__((ext_vector_type(4))) unsigned int uint4v;

static __device__ __forceinline__ unsigned short f2bf(float f) {
  unsigned u = __float_as_uint(f);
  u = (u + 0x7FFFu + ((u >> 16) & 1u)) >> 16;  // RNE
  return (unsigned short)u;
}

// pack two floats -> bf16 pair (round-half-up; inputs are tame normals)
static __device__ __forceinline__ unsigned pack2(float x, float y) {
  unsigned ux = __float_as_uint(x) + 0x8000u;
  unsigned uy = __float_as_uint(y) + 0x8000u;
  return __builtin_amdgcn_perm(uy, ux, 0x07060302u);
}

#define GLDS(g, l)                                                                     \
  __builtin_amdgcn_global_load_lds((const __attribute__((address_space(1))) void*)(g), \
                                   (__attribute__((address_space(3))) void*)(l), 16, 0, 0)

// ---------------------------------------------------------------- weight convert
__global__ __launch_bounds__(256) void cvt_w(const float* __restrict__ w0,
                                             const float* __restrict__ w1,
                                             const float* __restrict__ w2,
                                             const float* __restrict__ w3,
                                             unsigned short* __restrict__ o0,
                                             unsigned short* __restrict__ o1,
                                             unsigned short* __restrict__ o2,
                                             unsigned short* __restrict__ o3) {
  int bx = blockIdx.x;
  int seg = bx / 576;
  int t = bx - seg * 576;
  const float* s = seg == 0 ? w0 : seg == 1 ? w1 : seg == 2 ? w2 : w3;
  unsigned short* d = seg == 0 ? o0 : seg == 1 ? o1 : seg == 2 ? o2 : o3;
  long i = (long)t * 256 + threadIdx.x;
  float4 val = ((const float4*)s)[i];
  short4v o;
  o.x = (short)f2bf(val.x);
  o.y = (short)f2bf(val.y);
  o.z = (short)f2bf(val.z);
  o.w = (short)f2bf(val.w);
  *(short4v*)(d + 4 * i) = o;
}

// ---------------------------------------------------------------- proj Q/K
// C^T = W * A^T (swapped operands): lane holds s=..+ln (col), n=..+quad*4+r (row).
// A fp32 [8192,768] converted in-register; W bf16 via GLDS.
// out: [B,H,S,64] bf16, contiguous stores via LDS transpose.
__global__ __launch_bounds__(256) void projqk_gemm(const float* __restrict__ Aq,
                                                   const float* __restrict__ Ak,
                                                   const unsigned short* __restrict__ Wq,
                                                   const unsigned short* __restrict__ Wk,
                                                   unsigned short* __restrict__ Oq,
                                                   unsigned short* __restrict__ Ok) {
  constexpr int K = 768;
  __shared__ unsigned short As[128 * 32];
  __shared__ unsigned short Bs[128 * 32];
  __shared__ unsigned short Ts[128 * 136];

  const int bx = blockIdx.x;
  const int xcd = bx & 7;
  const int i = bx >> 3;  // 0..95
  const int op = i / 48;
  const int j = i - op * 48;
  const int m0 = ((j / 6) * 8 + xcd) << 7;
  const int n0 = (j % 6) << 7;
  const float* A = op ? Ak : Aq;
  const unsigned short* W = op ? Wk : Wq;
  unsigned short* O = op ? Ok : Oq;

  const int tid = threadIdx.x, lane = tid & 63, wave = tid >> 6;
  const int ln = lane & 15, quad = lane >> 4;
  const int wm = (wave & 1) << 6, wn = (wave >> 1) << 6;

  // A staging: thread covers rows ar, ar+64; 8 k-cols
  const int ar = tid >> 2, ac = (tid & 3) << 3;
  const float* gA0 = A + (long)(m0 + ar) * K + ac;
  const float* gA1 = A + (long)(m0 + ar + 64) * K + ac;
  unsigned short* lA0 = As + ar * 32 + ac;
  unsigned short* lA1 = As + (ar + 64) * 32 + ac;
  // W staging via GLDS
  const int o0 = tid << 4, o1 = 4096 + (tid << 4);
  const unsigned short* gB0 = W + (long)(n0 + (o0 >> 6)) * K + ((o0 >> 4) & 3) * 8;
  const unsigned short* gB1 = W + (long)(n0 + (o1 >> 6)) * K + ((o1 >> 4) & 3) * 8;
  unsigned short* lB0 = Bs + (o0 >> 1);
  unsigned short* lB1 = Bs + (o1 >> 1);

  f32x4 acc[4][4] = {};
  for (int k0 = 0; k0 < K; k0 += 32) {
    float4 a00 = *(const float4*)(gA0 + k0);
    float4 a01 = *(const float4*)(gA0 + k0 + 4);
    float4 a10 = *(const float4*)(gA1 + k0);
    float4 a11 = *(const float4*)(gA1 + k0 + 4);
    __syncthreads();
    GLDS(gB0 + k0, lB0);
    GLDS(gB1 + k0, lB1);
    uint4v p0, p1;
    p0.x = pack2(a00.x, a00.y);
    p0.y = pack2(a00.z, a00.w);
    p0.z = pack2(a01.x, a01.y);
    p0.w = pack2(a01.z, a01.w);
    p1.x = pack2(a10.x, a10.y);
    p1.y = pack2(a10.z, a10.w);
    p1.z = pack2(a11.x, a11.y);
    p1.w = pack2(a11.z, a11.w);
    *(uint4v*)lA0 = p0;
    *(uint4v*)lA1 = p1;
    __syncthreads();
    short8 af[4], bfr[4];
#pragma unroll
    for (int mi = 0; mi < 4; mi++)
      af[mi] = *(const short8*)(As + (wm + mi * 16 + ln) * 32 + quad * 8);
#pragma unroll
    for (int ni = 0; ni < 4; ni++)
      bfr[ni] = *(const short8*)(Bs + (wn + ni * 16 + ln) * 32 + quad * 8);
#pragma unroll
    for (int mi = 0; mi < 4; mi++)
#pragma unroll
      for (int ni = 0; ni < 4; ni++)  // swapped: A-op = W frag, B-op = A frag
        acc[mi][ni] =
            __builtin_amdgcn_mfma_f32_16x16x32_bf16(bfr[ni], af[mi], acc[mi][ni], 0, 0, 0);
  }

  __syncthreads();
#pragma unroll
  for (int mi = 0; mi < 4; mi++) {
#pragma unroll
    for (int ni = 0; ni < 4; ni++) {
      f32x4 v = acc[mi][ni];
      int s = wm + mi * 16 + ln;
      int n = wn + ni * 16 + quad * 4;
      uint2 w2;
      w2.x = pack2(v[0], v[1]);
      w2.y = pack2(v[2], v[3]);
      *(uint2*)(Ts + s * 136 + n) = w2;
    }
  }
  __syncthreads();
  const int part = tid & 7, sg0 = tid >> 3;  // 8x16B per 128B segment
#pragma unroll
  for (int p = 0; p < 8; p++) {
    int seg = sg0 + p * 32;  // 0..255: 128 s-rows x 2 heads
    int hh = seg >> 7, s = seg & 127;
    short8 val = *(const short8*)(Ts + s * 136 + hh * 64 + part * 8);
    int gs = m0 + s;
    int bb = gs >> 11, srow = gs & 2047;
    int head = (n0 >> 6) + hh;
    *(short8*)(O + (((long)(bb * 12 + head) * 2048 + srow) << 6) + part * 8) = val;
  }
}

// ---------------------------------------------------------------- proj V
// Normal orientation: lane holds d=..+ln (col), s=..+quad*4+r (row).
// out: [B,H,64,S] bf16 via LDS transpose.
__global__ __launch_bounds__(256) void projv_gemm(const float* __restrict__ Av,
                                                  const unsigned short* __restrict__ Wv,
                                                  unsigned short* __restrict__ Ov) {
  constexpr int K = 768;
  __shared__ unsigned short As[128 * 32];
  __shared__ unsigned short Bs[128 * 32];
  __shared__ unsigned short Ts[128 * 136];

  const int bx = blockIdx.x;
  const int xcd = bx & 7;
  const int i = bx >> 3;  // 0..47
  const int m0 = ((i / 6) * 8 + xcd) << 7;
  const int n0 = (i % 6) << 7;

  const int tid = threadIdx.x, lane = tid & 63, wave = tid >> 6;
  const int ln = lane & 15, quad = lane >> 4;
  const int wm = (wave & 1) << 6, wn = (wave >> 1) << 6;

  const int ar = tid >> 2, ac = (tid & 3) << 3;
  const float* gA0 = Av + (long)(m0 + ar) * K + ac;
  const float* gA1 = Av + (long)(m0 + ar + 64) * K + ac;
  unsigned short* lA0 = As + ar * 32 + ac;
  unsigned short* lA1 = As + (ar + 64) * 32 + ac;
  const int o0 = tid << 4, o1 = 4096 + (tid << 4);
  const unsigned short* gB0 = Wv + (long)(n0 + (o0 >> 6)) * K + ((o0 >> 4) & 3) * 8;
  const unsigned short* gB1 = Wv + (long)(n0 + (o1 >> 6)) * K + ((o1 >> 4) & 3) * 8;
  unsigned short* lB0 = Bs + (o0 >> 1);
  unsigned short* lB1 = Bs + (o1 >> 1);

  f32x4 acc[4][4] = {};
  for (int k0 = 0; k0 < K; k0 += 32) {
    float4 a00 = *(const float4*)(gA0 + k0);
    float4 a01 = *(const float4*)(gA0 + k0 + 4);
    float4 a10 = *(const float4*)(gA1 + k0);
    float4 a11 = *(const float4*)(gA1 + k0 + 4);
    __syncthreads();
    GLDS(gB0 + k0, lB0);
    GLDS(gB1 + k0, lB1);
    uint4v p0, p1;
    p0.x = pack2(a00.x, a00.y);
    p0.y = pack2(a00.z, a00.w);
    p0.z = pack2(a01.x, a01.y);
    p0.w = pack2(a01.z, a01.w);
    p1.x = pack2(a10.x, a10.y);
    p1.y = pack2(a10.z, a10.w);
    p1.z = pack2(a11.x, a11.y);
    p1.w = pack2(a11.z, a11.w);
    *(uint4v*)lA0 = p0;
    *(uint4v*)lA1 = p1;
    __syncthreads();
    short8 af[4], bfr[4];
#pragma unroll
    for (int mi = 0; mi < 4; mi++)
      af[mi] = *(const short8*)(As + (wm + mi * 16 + ln) * 32 + quad * 8);
#pragma unroll
    for (int ni = 0; ni < 4; ni++)
      bfr[ni] = *(const short8*)(Bs + (wn + ni * 16 + ln) * 32 + quad * 8);
#pragma unroll
    for (int mi = 0; mi < 4; mi++)
#pragma unroll
      for (int ni = 0; ni < 4; ni++)
        acc[mi][ni] =
            __builtin_amdgcn_mfma_f32_16x16x32_bf16(af[mi], bfr[ni], acc[mi][ni], 0, 0, 0);
  }

  __syncthreads();
#pragma unroll
  for (int mi = 0; mi < 4; mi++) {
#pragma unroll
    for (int ni = 0; ni < 4; ni++) {
      f32x4 v = acc[mi][ni];
      int d = wn + ni * 16 + ln;
      int s = wm + mi * 16 + quad * 4;
      uint2 w2;
      w2.x = pack2(v[0], v[1]);
      w2.y = pack2(v[2], v[3]);
      *(uint2*)(Ts + d * 136 + s) = w2;  // Tv[d][s]
    }
  }
  __syncthreads();
  const int part = tid & 15, r0 = tid >> 4;  // 16x16B per 256B d-row segment
  const int bb = m0 >> 11, sbase = m0 & 2047;
#pragma unroll
  for (int p = 0; p < 8; p++) {
    int d = r0 + p * 16;  // 0..127
    short8 val = *(const short8*)(Ts + d * 136 + part * 8);
    int head = (n0 >> 6) + (d >> 6);
    int dl = d & 63;
    *(short8*)(Ov + ((long)(bb * 12 + head) * 64 + dl) * 2048 + sbase + part * 8) = val;
  }
}

// ---------------------------------------------------------------- dense (bf16 in, fp32 out)
// Swapped operands: lane holds m=..+ln, n=..+quad*4+r (4 consecutive floats -> float4 store)
__global__ __launch_bounds__(256) void dense_gemm(const unsigned short* __restrict__ A,
                                                  const unsigned short* __restrict__ W,
                                                  const float* __restrict__ bias,
                                                  float* __restrict__ out) {
  constexpr int K = 768;
  __shared__ unsigned short As[128 * 32];
  __shared__ unsigned short Bs[128 * 32];
  const int bx = blockIdx.x;
  const int xcd = bx & 7;
  const int i = bx >> 3;
  const int m0 = ((i / 6) * 8 + xcd) << 7;
  const int n0 = (i % 6) << 7;

  const int tid = threadIdx.x, lane = tid & 63, wave = tid >> 6;
  const int ln = lane & 15, quad = lane >> 4;
  const int wm = (wave & 1) << 6, wn = (wave >> 1) << 6;

  const int o0 = tid << 4, o1 = 4096 + (tid << 4);
  const unsigned short* gA0 = A + (long)(m0 + (o0 >> 6)) * K + ((o0 >> 4) & 3) * 8;
  const unsigned short* gA1 = A + (long)(m0 + (o1 >> 6)) * K + ((o1 >> 4) & 3) * 8;
  const unsigned short* gB0 = W + (long)(n0 + (o0 >> 6)) * K + ((o0 >> 4) & 3) * 8;
  const unsigned short* gB1 = W + (long)(n0 + (o1 >> 6)) * K + ((o1 >> 4) & 3) * 8;
  unsigned short* lA0 = As + (o0 >> 1);
  unsigned short* lA1 = As + (o1 >> 1);
  unsigned short* lB0 = Bs + (o0 >> 1);
  unsigned short* lB1 = Bs + (o1 >> 1);

  f32x4 acc[4][4] = {};
  for (int k0 = 0; k0 < K; k0 += 32) {
    __syncthreads();
    GLDS(gA0 + k0, lA0);
    GLDS(gA1 + k0, lA1);
    GLDS(gB0 + k0, lB0);
    GLDS(gB1 + k0, lB1);
    __syncthreads();
    short8 af[4], bfr[4];
#pragma unroll
    for (int mi = 0; mi < 4; mi++)
      af[mi] = *(const short8*)(As + (wm + mi * 16 + ln) * 32 + quad * 8);
#pragma unroll
    for (int ni = 0; ni < 4; ni++)
      bfr[ni] = *(const short8*)(Bs + (wn + ni * 16 + ln) * 32 + quad * 8);
#pragma unroll
    for (int mi = 0; mi < 4; mi++)
#pragma unroll
      for (int ni = 0; ni < 4; ni++)
        acc[mi][ni] =
            __builtin_amdgcn_mfma_f32_16x16x32_bf16(bfr[ni], af[mi], acc[mi][ni], 0, 0, 0);
  }

#pragma unroll
  for (int mi = 0; mi < 4; mi++) {
    const int m = m0 + wm + mi * 16 + ln;
#pragma unroll
    for (int ni = 0; ni < 4; ni++) {
      const int n = n0 + wn + ni * 16 + quad * 4;
      f32x4 v = acc[mi][ni];
      float4 bv = *(const float4*)(bias + n);
      float4 st;
      st.x = v[0] + bv.x;
      st.y = v[1] + bv.y;
      st.z = v[2] + bv.z;
      st.w = v[3] + bv.w;
      *(float4*)(out + (long)m * 768 + n) = st;
    }
  }
}

// ---------------------------------------------------------------- flash attention (transposed)
__global__ __launch_bounds__(256, 3) void attn_kernel(const unsigned short* __restrict__ Qh,
                                                      const unsigned short* __restrict__ Kh,
                                                      const unsigned short* __restrict__ Vt,
                                                      unsigned short* __restrict__ outp) {
  constexpr int S = 2048;
  constexpr float CEXP = 0.18033688011112042f;  // (1/8)*log2(e)
  __shared__ unsigned short Ks[128 * 72];
  __shared__ unsigned short Vs[64 * 136];

  // XCD swizzle: all 16 pair-blocks of a (b,h) on one XCD -> K/V L2-resident
  const int bx = blockIdx.x;
  const int xcd = bx & 7;
  const int ii = bx >> 3;  // 0..95
  const int pr = ii & 15, grp = ii >> 4;  // grp 0..5
  const int bh = grp * 8 + xcd;           // 0..47
  const int h = bh % 12, b = bh / 12;
  const int qtA = pr, qtB = 31 - pr;
  const int tid = threadIdx.x, wave = tid >> 6, lane = tid & 63;
  const int ln = lane & 15, quad = lane >> 4;

  const unsigned short* Qg = Qh + (long)(b * 12 + h) * S * 64;
  const unsigned short* Kg = Kh + (long)(b * 12 + h) * S * 64;
  const unsigned short* Vg = Vt + (long)(b * 12 + h) * 64 * S;

  const int qrA = qtA * 64 + wave * 16 + ln;
  const int qrB = qtB * 64 + wave * 16 + ln;

  short8 bQa0 = *(const short8*)(Qg + qrA * 64 + quad * 8);
  short8 bQa1 = *(const short8*)(Qg + qrA * 64 + 32 + quad * 8);
  short8 bQb0 = *(const short8*)(Qg + qrB * 64 + quad * 8);
  short8 bQb1 = *(const short8*)(Qg + qrB * 64 + 32 + quad * 8);

  float mA = -1e30f, lA = 0.f, mB = -1e30f, lB = 0.f;
  f32x4 Oa[4] = {};
  f32x4 Obb[4] = {};
  unsigned pkA[8][2], pkB[8][2];

  const int nkA = (qtA >> 1) + 1;
  const int nkB = (qtB >> 1) + 1;
  const int l0 = ln + ((quad & 1) << 5);
  const bool hi = quad >= 2;

  for (int kt = 0; kt < nkB; kt++) {
    short8 kc[4], vc[4];
#pragma unroll
    for (int i = 0; i < 4; i++) {
      int c = tid + i * 256;
      kc[i] = *(const short8*)(Kg + (long)kt * 8192 + c * 8);
      vc[i] = *(const short8*)(Vg + (long)(c >> 4) * S + kt * 128 + (c & 15) * 8);
    }
    __syncthreads();
#pragma unroll
    for (int i = 0; i < 4; i++) {
      int c = tid + i * 256;
      *(short8*)(Ks + (c >> 3) * 72 + (c & 7) * 8) = kc[i];
      *(short8*)(Vs + (c >> 4) * 136 + (c & 15) * 8) = vc[i];
    }
    __syncthreads();

    const bool actA = kt < nkA;
    const bool dgA = (kt == nkA - 1);
    const bool dgB = (kt == nkB - 1);
    const int limA = actA ? (dgA ? ((qtA & 1) ? 8 : 4) : 8) : 0;
    const int limB = dgB ? ((qtB & 1) ? 8 : 4) : 8;
    const int limQ = limA > limB ? limA : limB;

    f32x4 sa[8], sb[8];
#pragma unroll
    for (int ni = 0; ni < 8; ni++) {
      sa[ni] = (f32x4){0.f, 0.f, 0.f, 0.f};
      sb[ni] = (f32x4){0.f, 0.f, 0.f, 0.f};
    }
#pragma unroll
    for (int ni = 0; ni < 8; ni++) {
      if (ni < limQ) {
        short8 k0 = *(const short8*)(Ks + (ni * 16 + ln) * 72 + quad * 8);
        short8 k1 = *(const short8*)(Ks + (ni * 16 + ln) * 72 + 32 + quad * 8);
        if (ni < limA) {
          sa[ni] = __builtin_amdgcn_mfma_f32_16x16x32_bf16(k0, bQa0, sa[ni], 0, 0, 0);
          sa[ni] = __builtin_amdgcn_mfma_f32_16x16x32_bf16(k1, bQa1, sa[ni], 0, 0, 0);
        }
        if (ni < limB) {
          sb[ni] = __builtin_amdgcn_mfma_f32_16x16x32_bf16(k0, bQb0, sb[ni], 0, 0, 0);
          sb[ni] = __builtin_amdgcn_mfma_f32_16x16x32_bf16(k1, bQb1, sb[ni], 0, 0, 0);
        }
      }
    }

    auto soft = [&](f32x4* s, unsigned (&pk)[8][2], float& m, float& l, f32x4* O, int lim,
                    bool dg, int qrow) {
      if (dg) {
#pragma unroll
        for (int ni = 0; ni < 8; ni++)
          if (ni < lim)
#pragma unroll
            for (int r = 0; r < 4; r++) {
              int key = kt * 128 + ni * 16 + quad * 4 + r;
              if (key > qrow) s[ni][r] = -1e30f;
            }
      }
      float mx = -1e30f;
#pragma unroll
      for (int ni = 0; ni < 8; ni++)
        if (ni < lim)
          mx = fmaxf(mx, fmaxf(fmaxf(s[ni][0], s[ni][1]), fmaxf(s[ni][2], s[ni][3])));
      mx = fmaxf(mx, __shfl_xor(mx, 16));
      mx = fmaxf(mx, __shfl_xor(mx, 32));
      float mnew = fmaxf(m, mx);
      float alpha = exp2f((m - mnew) * CEXP);
      m = mnew;
      const float mc = mnew * CEXP;
      float sum = 0.f;
#pragma unroll
      for (int ni = 0; ni < 8; ni++) {
        if (ni < lim) {
          float p0 = exp2f(fmaf(s[ni][0], CEXP, -mc));
          float p1 = exp2f(fmaf(s[ni][1], CEXP, -mc));
          float p2 = exp2f(fmaf(s[ni][2], CEXP, -mc));
          float p3 = exp2f(fmaf(s[ni][3], CEXP, -mc));
          sum += (p0 + p1) + (p2 + p3);
          pk[ni][0] = __builtin_amdgcn_perm(__float_as_uint(p1), __float_as_uint(p0), 0x07060302u);
          pk[ni][1] = __builtin_amdgcn_perm(__float_as_uint(p3), __float_as_uint(p2), 0x07060302u);
        } else {
          pk[ni][0] = 0u;
          pk[ni][1] = 0u;
        }
      }
      sum += __shfl_xor(sum, 16);
      sum += __shfl_xor(sum, 32);
      l = l * alpha + sum;
#pragma unroll
      for (int di = 0; di < 4; di++) O[di] *= alpha;
    };
    if (actA) soft(sa, pkA, mA, lA, Oa, limA, dgA, qrA);
    soft(sb, pkB, mB, lB, Obb, limB, dgB, qrB);

    auto mkB = [&](unsigned (&pk)[8][2], int kk) -> short8 {
      unsigned va0 = (unsigned)__shfl((int)pk[2 * kk][0], l0, 64);
      unsigned vb0 = (unsigned)__shfl((int)pk[2 * kk + 1][0], l0, 64);
      unsigned va1 = (unsigned)__shfl((int)pk[2 * kk][1], l0, 64);
      unsigned vb1 = (unsigned)__shfl((int)pk[2 * kk + 1][1], l0, 64);
      unsigned va2 = (unsigned)__shfl((int)pk[2 * kk][0], l0 + 16, 64);
      unsigned vb2 = (unsigned)__shfl((int)pk[2 * kk + 1][0], l0 + 16, 64);
      unsigned va3 = (unsigned)__shfl((int)pk[2 * kk][1], l0 + 16, 64);
      unsigned vb3 = (unsigned)__shfl((int)pk[2 * kk + 1][1], l0 + 16, 64);
      uint4v tv;
      tv.x = hi ? vb0 : va0;
      tv.y = hi ? vb1 : va1;
      tv.z = hi ? vb2 : va2;
      tv.w = hi ? vb3 : va3;
      return __builtin_bit_cast(short8, tv);
    };

#pragma unroll
    for (int kk = 0; kk < 4; kk++) {
      short8 Bb = mkB(pkB, kk);
      short8 Ba;
      if (actA) Ba = mkB(pkA, kk);
#pragma unroll
      for (int di = 0; di < 4; di++) {
        short8 aV = *(const short8*)(Vs + (di * 16 + ln) * 136 + kk * 32 + quad * 8);
        Obb[di] = __builtin_amdgcn_mfma_f32_16x16x32_bf16(aV, Bb, Obb[di], 0, 0, 0);
        if (actA) Oa[di] = __builtin_amdgcn_mfma_f32_16x16x32_bf16(aV, Ba, Oa[di], 0, 0, 0);
      }
    }
  }

  // ---- epilogue: LDS transpose (reuse Ks) -> contiguous 128B-row stores
  __syncthreads();
  unsigned short* Ts = Ks;  // [128 rows][72]: rows 0..63 = segA, 64..127 = segB
  {
    float rlA = 1.0f / lA, rlB = 1.0f / lB;
    const int row = wave * 16 + ln;
#pragma unroll
    for (int di = 0; di < 4; di++) {
      uint2 wa, wb;
      wa.x = pack2(Oa[di][0] * rlA, Oa[di][1] * rlA);
      wa.y = pack2(Oa[di][2] * rlA, Oa[di][3] * rlA);
      wb.x = pack2(Obb[di][0] * rlB, Obb[di][1] * rlB);
      wb.y = pack2(Obb[di][2] * rlB, Obb[di][3] * rlB);
      *(uint2*)(Ts + row * 72 + di * 16 + quad * 4) = wa;
      *(uint2*)(Ts + (row + 64) * 72 + di * 16 + quad * 4) = wb;
    }
  }
  __syncthreads();
  const int part = tid & 7, r0 = tid >> 3;  // 32 rows/pass x 8x16B
#pragma unroll
  for (int p = 0; p < 4; p++) {
    int row = r0 + p * 32;  // 0..127
    int seg = row >> 6, qq = row & 63;
    int qrow = (seg ? qtB : qtA) * 64 + qq;
    short8 val = *(const short8*)(Ts + row * 72 + part * 8);
    *(short8*)(outp + ((long)b * S + qrow) * 768 + h * 64 + part * 8) = val;
  }
}

// ---------------------------------------------------------------- launch
extern "C" void kernel_launch(void* const* d_in, const int* in_sizes, int n_in,
                              void* d_out, int out_size, void* d_ws, size_t ws_size,
                              hipStream_t stream) {
  const float* q = (const float*)d_in[0];
  const float* k = (const float*)d_in[1];
  const float* v = (const float*)d_in[2];
  // d_in[3] = mask: causal triu(k=1) by construction — implemented analytically
  const float* wq = (const float*)d_in[4];
  const float* wk = (const float*)d_in[5];
  const float* wv = (const float*)d_in[6];
  const float* wd = (const float*)d_in[7];
  const float* bd = (const float*)d_in[8];
  float* out = (float*)d_out;

  const long QKV = 4L * 2048 * 768;  // 6291456
  const long WN = 768L * 768;        // 589824
  if (ws_size < (size_t)(4 * QKV + 4 * WN) * 2) return;

  unsigned short* wqb = (unsigned short*)d_ws;
  unsigned short* wkb = wqb + WN;
  unsigned short* wvb = wkb + WN;
  unsigned short* wdb = wvb + WN;
  unsigned short* qh = wdb + WN;
  unsigned short* kh = qh + QKV;
  unsigned short* vt = kh + QKV;
  unsigned short* at = vt + QKV;

  cvt_w<<<2304, 256, 0, stream>>>(wq, wk, wv, wd, wqb, wkb, wvb, wdb);
  projqk_gemm<<<768, 256, 0, stream>>>(q, k, wqb, wkb, qh, kh);
  projv_gemm<<<384, 256, 0, stream>>>(v, wvb, vt);
  attn_kernel<<<768, 256, 0, stream>>>(qh, kh, vt, at);
  dense_gemm<<<384, 256, 0, stream>>>(at, wdb, bd, out);
}